// Round 1
// baseline (502.874 us; speedup 1.0000x reference)
//
#include <hip/hip_runtime.h>
#include <math.h>

#define EPSN 1e-8f

__device__ __forceinline__ float d4(const float4 a, const float4 b) {
    return a.x*b.x + a.y*b.y + a.z*b.z + a.w*b.w;
}

// One wave (64 lanes) per batch element. lane = feature dim d.
// Block = 128 threads = 2 waves = 2 batch elements. Static LDS 38.7 KB -> 4 blocks/CU.
__global__ __launch_bounds__(128, 2)
void infer_kernel(const float* __restrict__ content,   // [B,16,64]
                  const float* __restrict__ types,     // [B,16,3]
                  const float* __restrict__ conf,      // [B,16]
                  const float* __restrict__ Sg,        // [B,32,64]
                  const float* __restrict__ W_ante,    // [64,64]
                  const float* __restrict__ W_cons,    // [64,128]
                  const float* __restrict__ W_gw,      // [64,128]
                  const float* __restrict__ W_gb,      // [64]
                  const float* __restrict__ lft,       // [1]
                  float* __restrict__ out,             // [B*32*64 + B]
                  int B)
{
    const int l = threadIdx.x & 63;      // lane = dim d
    const int w = threadIdx.x >> 6;      // wave in block
    const int b = blockIdx.x * 2 + w;    // batch element
    if (b >= B) return;

    // per-wave LDS slices (row pitch 68 floats = 272 B: 16B-aligned, conflict-benign)
    __shared__ float s_cont[2][16*68];   // content rows; later reused for new_fact
    __shared__ float s_scr [2][16*68];   // ante rows; later reused for matched
    __shared__ float s_ms  [2][16*20];   // match_scores [16][16] pad 20
    __shared__ float s_S   [2][32*68];   // scratchpad S
    __shared__ float s_sm  [2][160];     // alpha[32] | ncd@32 | nad@48 | conf@64 | pf@80 | pr@96 | fire@112 | dconf@128

    float* cont = s_cont[w];
    float* scr  = s_scr[w];
    float* ms   = s_ms[w];
    float* sS   = s_S[w];
    float* sm   = s_sm[w];

    const float thr = expf(lft[0]);

    // ---------------- load content (regs + LDS), conf/types, S ----------------
    float c[16];
    const float* cb = content + ((size_t)b * 16) * 64;
    #pragma unroll
    for (int k = 0; k < 16; k++) {
        float v = cb[k*64 + l];
        c[k] = v;
        cont[k*68 + l] = v;
    }
    if (l < 16) {
        sm[64 + l] = conf[(size_t)b*16 + l];
        sm[80 + l] = types[((size_t)b*16 + l)*3 + 0];   // p_fact
        sm[96 + l] = types[((size_t)b*16 + l)*3 + 1];   // p_rule
    }
    const float* Sb = Sg + ((size_t)b * 32) * 64;
    #pragma unroll
    for (int m = 0; m < 32; m++) sS[m*68 + l] = Sb[m*64 + l];

    // ---------------- content norm denoms -> sm[32+k] ----------------
    {
        const int k = l & 15, q = l >> 4;
        const float4* row = (const float4*)&cont[k*68 + q*16];
        float s2 = 0.f;
        #pragma unroll
        for (int i = 0; i < 4; i++) { float4 v = row[i]; s2 += d4(v, v); }
        s2 += __shfl_xor(s2, 16, 64);
        s2 += __shfl_xor(s2, 32, 64);
        if (l < 16) sm[32 + l] = fmaxf(sqrtf(s2), EPSN);
    }

    // ---------------- ante = content @ W_ante^T  (W row in regs) ----------------
    float4 wA[16], wB[16];
    {
        const float4* wr = (const float4*)(W_ante + (size_t)l * 64);
        #pragma unroll
        for (int i = 0; i < 16; i++) wA[i] = wr[i];
    }
    #pragma unroll
    for (int k = 0; k < 16; k++) {
        const float4* cr = (const float4*)&cont[k*68];
        float a = 0.f;
        #pragma unroll
        for (int i = 0; i < 16; i++) a += d4(cr[i], wA[i]);
        scr[k*68 + l] = a;
    }

    // ---------------- ante norm denoms -> sm[48+k] ----------------
    {
        const int k = l & 15, q = l >> 4;
        const float4* row = (const float4*)&scr[k*68 + q*16];
        float s2 = 0.f;
        #pragma unroll
        for (int i = 0; i < 4; i++) { float4 v = row[i]; s2 += d4(v, v); }
        s2 += __shfl_xor(s2, 16, 64);
        s2 += __shfl_xor(s2, 32, 64);
        if (l < 16) sm[48 + l] = fmaxf(sqrtf(s2), EPSN);
    }

    // ---------------- dots + match_scores: lane -> (k = l&15, 4 j's) ----------------
    {
        const int k = l & 15, jg = l >> 4;
        const float4* ar = (const float4*)&scr[k*68];
        const float4* c0 = (const float4*)&cont[(jg*4+0)*68];
        const float4* c1 = (const float4*)&cont[(jg*4+1)*68];
        const float4* c2 = (const float4*)&cont[(jg*4+2)*68];
        const float4* c3 = (const float4*)&cont[(jg*4+3)*68];
        float d0 = 0, d1 = 0, d2 = 0, d3 = 0;
        #pragma unroll
        for (int i = 0; i < 16; i++) {
            float4 a = ar[i];
            d0 += d4(a, c0[i]); d1 += d4(a, c1[i]);
            d2 += d4(a, c2[i]); d3 += d4(a, c3[i]);
        }
        const float na = sm[48 + k];
        ms[k*20 + jg*4+0] = (d0 / (na * sm[32 + jg*4+0])) * sm[80 + jg*4+0];
        ms[k*20 + jg*4+1] = (d1 / (na * sm[32 + jg*4+1])) * sm[80 + jg*4+1];
        ms[k*20 + jg*4+2] = (d2 / (na * sm[32 + jg*4+2])) * sm[80 + jg*4+2];
        ms[k*20 + jg*4+3] = (d3 / (na * sm[32 + jg*4+3])) * sm[80 + jg*4+3];
    }

    // ---------------- match_strength -> fire / derived_conf (lanes 0..15) ----------------
    if (l < 16) {
        const float4* mr = (const float4*)&ms[l*20];
        const float4* cf = (const float4*)&sm[64];
        float str = 0.f;
        #pragma unroll
        for (int i = 0; i < 4; i++) str += d4(mr[i], cf[i]);
        float z = (str - thr) * 2.0f;                 // (x - thr) / 0.5
        float fire = sm[96 + l] / (1.0f + expf(-z));  // sigmoid * p_rule
        sm[112 + l] = fire;
        sm[128 + l] = fire * sm[64 + l];              // derived_conf
    }

    // ---------------- matched[k][d] = sum_j ms[k][j] * content[j][d] ----------------
    float mt[16];
    #pragma unroll
    for (int k = 0; k < 16; k++) {
        const float4* mr = (const float4*)&ms[k*20];
        float m = 0.f;
        #pragma unroll
        for (int i = 0; i < 4; i++) {
            float4 m4 = mr[i];
            m += m4.x*c[4*i+0] + m4.y*c[4*i+1] + m4.z*c[4*i+2] + m4.w*c[4*i+3];
        }
        mt[k] = m;
    }
    #pragma unroll
    for (int k = 0; k < 16; k++) scr[k*68 + l] = mt[k];   // ante dead -> matched

    // ---------------- new_fact = [content|matched] @ W_cons^T ----------------
    float nf[16];
    {
        const float4* wr = (const float4*)(W_cons + (size_t)l * 128);
        #pragma unroll
        for (int i = 0; i < 16; i++) wA[i] = wr[i];
    }
    #pragma unroll
    for (int k = 0; k < 16; k++) {
        const float4* cr = (const float4*)&cont[k*68];
        float a = 0.f;
        #pragma unroll
        for (int i = 0; i < 16; i++) a += d4(cr[i], wA[i]);
        nf[k] = a;
    }
    {
        const float4* wr = (const float4*)(W_cons + (size_t)l * 128 + 64);
        #pragma unroll
        for (int i = 0; i < 16; i++) wA[i] = wr[i];
    }
    #pragma unroll
    for (int k = 0; k < 16; k++) {
        const float4* mr = (const float4*)&scr[k*68];
        float a = nf[k];
        #pragma unroll
        for (int i = 0; i < 16; i++) a += d4(mr[i], wA[i]);
        nf[k] = a;
    }
    // content dead -> store new_fact over cont buffer
    #pragma unroll
    for (int k = 0; k < 16; k++) cont[k*68 + l] = nf[k];

    // ---------------- gamma weights to regs ----------------
    {
        const float4* w1 = (const float4*)(W_gw + (size_t)l * 128);
        const float4* w2 = (const float4*)(W_gw + (size_t)l * 128 + 64);
        #pragma unroll
        for (int i = 0; i < 16; i++) { wA[i] = w1[i]; wB[i] = w2[i]; }
    }
    const float gb = W_gb[l];

    // ---------------- initial S norm denoms (m = l&31 layout, kept in reg) ----------------
    const int m = l & 31, h = l >> 5;
    float nsd;
    {
        const float4* sr = (const float4*)&sS[m*68 + h*32];
        float s2 = 0.f;
        #pragma unroll
        for (int i = 0; i < 8; i++) { float4 v = sr[i]; s2 += d4(v, v); }
        s2 += __shfl_xor(s2, 32, 64);
        nsd = fmaxf(sqrtf(s2), EPSN);
    }

    // ---------------- sequential scan over K rules ----------------
    #pragma unroll 1
    for (int k = 0; k < 16; k++) {
        const float fire = sm[112 + k];      // wave-uniform
        if (fire <= 0.1f) continue;          // reference: where(fire>0.1, S_w, S)
        const float dck = sm[128 + k];

        // ||cand||
        float dcand;
        {
            const int q = l >> 4;
            const float4* cr = (const float4*)&cont[k*68 + q*16];
            float s2 = 0.f;
            #pragma unroll
            for (int i = 0; i < 4; i++) { float4 v = cr[i]; s2 += d4(v, v); }
            s2 += __shfl_xor(s2, 16, 64);
            s2 += __shfl_xor(s2, 32, 64);
            dcand = fmaxf(sqrtf(s2), EPSN);
        }

        // dot[m] = cand . S[m]  (half-split over d, combine at xor 32)
        float dt = 0.f;
        {
            const float4* sr = (const float4*)&sS[m*68 + h*32];
            const float4* cr = (const float4*)&cont[k*68 + h*32];
            #pragma unroll
            for (int i = 0; i < 8; i++) dt += d4(sr[i], cr[i]);
            dt += __shfl_xor(dt, 32, 64);
        }
        const float sc = dt / (dcand * nsd);

        // softmax(4*s) over 32 slots (lanes duplicated at +32 stay consistent)
        const float x = sc * 4.0f;
        float mx = x;
        mx = fmaxf(mx, __shfl_xor(mx, 1, 64));
        mx = fmaxf(mx, __shfl_xor(mx, 2, 64));
        mx = fmaxf(mx, __shfl_xor(mx, 4, 64));
        mx = fmaxf(mx, __shfl_xor(mx, 8, 64));
        mx = fmaxf(mx, __shfl_xor(mx, 16, 64));
        const float e = expf(x - mx);
        float se = e;
        se += __shfl_xor(se, 1, 64);
        se += __shfl_xor(se, 2, 64);
        se += __shfl_xor(se, 4, 64);
        se += __shfl_xor(se, 8, 64);
        se += __shfl_xor(se, 16, 64);
        const float alpha = e / se;

        // argmax(alpha), first index on ties
        float av = alpha; int ai = m;
        #pragma unroll
        for (int msk = 1; msk <= 16; msk <<= 1) {
            float ov = __shfl_xor(av, msk, 64);
            int   oi = __shfl_xor(ai, msk, 64);
            if (ov > av || (ov == av && oi < ai)) { av = ov; ai = oi; }
        }
        const int best = ai;                 // wave-uniform

        if (l < 32) sm[l] = alpha;           // alpha -> LDS for d-layout update

        // gamma = sigmoid([best_slot|cand] @ W_gw^T + b)
        float g = gb;
        {
            const float4* br = (const float4*)&sS[best*68];
            const float4* cr = (const float4*)&cont[k*68];
            #pragma unroll
            for (int i = 0; i < 16; i++) {
                g += d4(br[i], wA[i]);
                g += d4(cr[i], wB[i]);
            }
        }
        const float gamma = 1.0f / (1.0f + expf(-g));
        const float cd  = cont[k*68 + l];
        const float bsd = sS[best*68 + l];
        const float ncd = gamma * cd + (1.0f - gamma) * bsd;

        // S[m][d] += dconf * alpha[m] * (new_content[d] - S[m][d])
        #pragma unroll
        for (int mg = 0; mg < 8; mg++) {
            float4 a4 = *(const float4*)&sm[mg*4];
            int base = (mg*4) * 68 + l;
            float s0 = sS[base        ]; sS[base        ] = fmaf(dck*a4.x, ncd - s0, s0);
            float s1 = sS[base +  68  ]; sS[base +  68  ] = fmaf(dck*a4.y, ncd - s1, s1);
            float s2v= sS[base + 136  ]; sS[base + 136  ] = fmaf(dck*a4.z, ncd - s2v, s2v);
            float s3 = sS[base + 204  ]; sS[base + 204  ] = fmaf(dck*a4.w, ncd - s3, s3);
        }

        // refresh S norm denom for my slot
        {
            const float4* sr = (const float4*)&sS[m*68 + h*32];
            float s2 = 0.f;
            #pragma unroll
            for (int i = 0; i < 8; i++) { float4 v = sr[i]; s2 += d4(v, v); }
            s2 += __shfl_xor(s2, 32, 64);
            nsd = fmaxf(sqrtf(s2), EPSN);
        }
    }

    // ---------------- write S_new and best_derived_conf ----------------
    float* outS = out + ((size_t)b * 32) * 64;
    #pragma unroll
    for (int mm = 0; mm < 32; mm++) outS[mm*64 + l] = sS[mm*68 + l];

    if (l == 0) {
        float mxv = sm[128];
        #pragma unroll
        for (int k = 1; k < 16; k++) mxv = fmaxf(mxv, sm[128 + k]);
        out[(size_t)B * 2048 + b] = mxv;
    }
}

extern "C" void kernel_launch(void* const* d_in, const int* in_sizes, int n_in,
                              void* d_out, int out_size, void* d_ws, size_t ws_size,
                              hipStream_t stream) {
    const float* content = (const float*)d_in[0];
    const float* types   = (const float*)d_in[1];
    const float* conf    = (const float*)d_in[2];
    const float* S       = (const float*)d_in[3];
    const float* W_ante  = (const float*)d_in[4];
    const float* W_cons  = (const float*)d_in[5];
    const float* W_gw    = (const float*)d_in[6];
    const float* W_gb    = (const float*)d_in[7];
    const float* lft     = (const float*)d_in[8];

    const int B = in_sizes[0] / (16 * 64);
    dim3 grid((B + 1) / 2), block(128);
    hipLaunchKernelGGL(infer_kernel, grid, block, 0, stream,
                       content, types, conf, S, W_ante, W_cons, W_gw, W_gb, lft,
                       (float*)d_out, B);
}

// Round 2
// 462.084 us; speedup vs baseline: 1.0883x; 1.0883x over previous
//
#include <hip/hip_runtime.h>
#include <math.h>

typedef float v2f __attribute__((ext_vector_type(2)));
typedef float v4f __attribute__((ext_vector_type(4)));

#define EPSN 1e-8f

__device__ __forceinline__ float hsum(v2f a) { return a.x + a.y; }

__device__ __forceinline__ void pk4(v2f& acc, v4f a, v4f b) {
    acc += a.xy * b.xy;
    acc += a.zw * b.zw;
}

// ============================ Kernel 1: dense phase ============================
// One wave per batch. lane = output dim. No S / no scan -> small LDS, high occupancy.
// Stages new_fact + (fire, dconf, ||cand||) into d_out's per-batch S slot:
//   out[b*2048 + k*64 + d]   = new_fact[k][d]      (k = 0..15)
//   out[b*2048 + 1024 + l]   = fire[16] | dconf[16] | ncand[16]  (l = 0..47)
//   out[B*2048 + b]          = best_derived_conf (final output tail)
__global__ __launch_bounds__(128, 4)
void dense_kernel(const float* __restrict__ content,   // [B,16,64]
                  const float* __restrict__ types,     // [B,16,3]
                  const float* __restrict__ conf,      // [B,16]
                  const float* __restrict__ W_ante,    // [64,64]
                  const float* __restrict__ W_cons,    // [64,128]
                  const float* __restrict__ lft,       // [1]
                  float* __restrict__ out, int B)
{
    const int l = threadIdx.x & 63;
    const int w = threadIdx.x >> 6;
    const int b = blockIdx.x * 2 + w;
    if (b >= B) return;

    __shared__ float s_cont[2][16*68];   // content -> later new_fact
    __shared__ float s_scr [2][16*68];   // ante -> later matched
    __shared__ float s_ms  [2][16*20];   // match_scores
    __shared__ float s_sm  [2][96];      // conf@0 pf@16 pr@32 cn@48 an@64
    float* cont = s_cont[w];
    float* scr  = s_scr[w];
    float* ms   = s_ms[w];
    float* sm   = s_sm[w];

    const float thr = expf(lft[0]);

    // load content (regs + LDS), conf/types
    float c[16];
    const float* cb = content + ((size_t)b << 10);
    #pragma unroll
    for (int k = 0; k < 16; k++) {
        float v = cb[(k << 6) + l];
        c[k] = v;
        cont[k*68 + l] = v;
    }
    if (l < 16) {
        sm[0  + l] = conf[((size_t)b << 4) + l];
        sm[16 + l] = types[(((size_t)b << 4) + l)*3 + 0];   // p_fact
        sm[32 + l] = types[(((size_t)b << 4) + l)*3 + 1];   // p_rule
    }

    // content norms -> sm[48+k]
    {
        const int k = l & 15, q = l >> 4;
        const v4f* row = (const v4f*)&cont[k*68 + q*16];
        v2f s2 = {0.f, 0.f};
        #pragma unroll
        for (int i = 0; i < 4; i++) { v4f v = row[i]; pk4(s2, v, v); }
        float s = hsum(s2);
        s += __shfl_xor(s, 16, 64);
        s += __shfl_xor(s, 32, 64);
        if (l < 16) sm[48 + l] = fmaxf(sqrtf(s), EPSN);
    }

    // ante = content @ W_ante^T (W row resident in regs as v2f pairs)
    v2f wA[32];
    {
        const v4f* wr = (const v4f*)(W_ante + ((size_t)l << 6));
        #pragma unroll
        for (int i = 0; i < 16; i++) { v4f v = wr[i]; wA[2*i] = v.xy; wA[2*i+1] = v.zw; }
    }
    #pragma unroll
    for (int k = 0; k < 16; k++) {
        const v4f* cr = (const v4f*)&cont[k*68];
        v2f a = {0.f, 0.f};
        #pragma unroll
        for (int i = 0; i < 16; i++) { v4f v = cr[i]; a += v.xy*wA[2*i]; a += v.zw*wA[2*i+1]; }
        scr[k*68 + l] = hsum(a);
    }

    // ante norms -> sm[64+k]
    {
        const int k = l & 15, q = l >> 4;
        const v4f* row = (const v4f*)&scr[k*68 + q*16];
        v2f s2 = {0.f, 0.f};
        #pragma unroll
        for (int i = 0; i < 4; i++) { v4f v = row[i]; pk4(s2, v, v); }
        float s = hsum(s2);
        s += __shfl_xor(s, 16, 64);
        s += __shfl_xor(s, 32, 64);
        if (l < 16) sm[64 + l] = fmaxf(sqrtf(s), EPSN);
    }

    // dots + match_scores: lane -> (k = l&15, 4 j's)
    {
        const int k = l & 15, jg4 = (l >> 4) * 4;
        const v4f* ar = (const v4f*)&scr[k*68];
        const v4f* c0 = (const v4f*)&cont[(jg4+0)*68];
        const v4f* c1 = (const v4f*)&cont[(jg4+1)*68];
        const v4f* c2 = (const v4f*)&cont[(jg4+2)*68];
        const v4f* c3 = (const v4f*)&cont[(jg4+3)*68];
        v2f d0 = {0,0}, d1 = {0,0}, d2 = {0,0}, d3 = {0,0};
        #pragma unroll
        for (int i = 0; i < 16; i++) {
            v4f a = ar[i];
            v4f x0 = c0[i]; d0 += a.xy*x0.xy; d0 += a.zw*x0.zw;
            v4f x1 = c1[i]; d1 += a.xy*x1.xy; d1 += a.zw*x1.zw;
            v4f x2 = c2[i]; d2 += a.xy*x2.xy; d2 += a.zw*x2.zw;
            v4f x3 = c3[i]; d3 += a.xy*x3.xy; d3 += a.zw*x3.zw;
        }
        const float na = sm[64 + k];
        v4f res;
        res.x = (hsum(d0) / (na * sm[48 + jg4+0])) * sm[16 + jg4+0];
        res.y = (hsum(d1) / (na * sm[48 + jg4+1])) * sm[16 + jg4+1];
        res.z = (hsum(d2) / (na * sm[48 + jg4+2])) * sm[16 + jg4+2];
        res.w = (hsum(d3) / (na * sm[48 + jg4+3])) * sm[16 + jg4+3];
        *(v4f*)&ms[k*20 + jg4] = res;
    }

    // match_strength -> fire / dconf (lanes 0..15) -> staging + tail
    float dc_l = 0.f;
    if (l < 16) {
        const v4f* mr = (const v4f*)&ms[l*20];
        const v4f* cf = (const v4f*)&sm[0];
        v2f st = {0.f, 0.f};
        #pragma unroll
        for (int i = 0; i < 4; i++) { v4f m4 = mr[i]; v4f f4 = cf[i]; st += m4.xy*f4.xy; st += m4.zw*f4.zw; }
        float str = hsum(st);
        float fire = sm[32 + l] / (1.0f + expf(-(str - thr) * 2.0f));
        float dcf  = fire * sm[0 + l];
        out[((size_t)b << 11) + 1024 + l] = fire;
        out[((size_t)b << 11) + 1040 + l] = dcf;
        dc_l = dcf;
    }
    {
        float mv = dc_l;
        mv = fmaxf(mv, __shfl_xor(mv, 1, 64));
        mv = fmaxf(mv, __shfl_xor(mv, 2, 64));
        mv = fmaxf(mv, __shfl_xor(mv, 4, 64));
        mv = fmaxf(mv, __shfl_xor(mv, 8, 64));
        if (l == 0) out[((size_t)B << 11) + b] = mv;
    }

    // matched[k][d] = sum_j ms[k][j] * content[j][d]  (from regs c[])
    float mt[16];
    #pragma unroll
    for (int k = 0; k < 16; k++) {
        const v4f* mr = (const v4f*)&ms[k*20];
        v2f m2 = {0.f, 0.f};
        #pragma unroll
        for (int i = 0; i < 4; i++) {
            v4f m4 = mr[i];
            v2f clo = {c[4*i+0], c[4*i+1]};
            v2f chi = {c[4*i+2], c[4*i+3]};
            m2 += m4.xy*clo; m2 += m4.zw*chi;
        }
        mt[k] = hsum(m2);
    }
    #pragma unroll
    for (int k = 0; k < 16; k++) scr[k*68 + l] = mt[k];   // ante dead -> matched

    // new_fact = content @ W1^T + matched @ W2^T
    float nf[16];
    {
        const v4f* wr = (const v4f*)(W_cons + ((size_t)l << 7));
        #pragma unroll
        for (int i = 0; i < 16; i++) { v4f v = wr[i]; wA[2*i] = v.xy; wA[2*i+1] = v.zw; }
    }
    #pragma unroll
    for (int k = 0; k < 16; k++) {
        const v4f* cr = (const v4f*)&cont[k*68];
        v2f a = {0.f, 0.f};
        #pragma unroll
        for (int i = 0; i < 16; i++) { v4f v = cr[i]; a += v.xy*wA[2*i]; a += v.zw*wA[2*i+1]; }
        nf[k] = hsum(a);
    }
    {
        const v4f* wr = (const v4f*)(W_cons + ((size_t)l << 7) + 64);
        #pragma unroll
        for (int i = 0; i < 16; i++) { v4f v = wr[i]; wA[2*i] = v.xy; wA[2*i+1] = v.zw; }
    }
    #pragma unroll
    for (int k = 0; k < 16; k++) {
        const v4f* mr = (const v4f*)&scr[k*68];
        v2f a = {0.f, 0.f};
        #pragma unroll
        for (int i = 0; i < 16; i++) { v4f v = mr[i]; a += v.xy*wA[2*i]; a += v.zw*wA[2*i+1]; }
        nf[k] += hsum(a);
    }

    // nf -> LDS (for norms) + global staging
    #pragma unroll
    for (int k = 0; k < 16; k++) {
        cont[k*68 + l] = nf[k];
        out[((size_t)b << 11) + (k << 6) + l] = nf[k];
    }

    // ||cand|| -> staging
    {
        const int k = l & 15, q = l >> 4;
        const v4f* row = (const v4f*)&cont[k*68 + q*16];
        v2f s2 = {0.f, 0.f};
        #pragma unroll
        for (int i = 0; i < 4; i++) { v4f v = row[i]; pk4(s2, v, v); }
        float s = hsum(s2);
        s += __shfl_xor(s, 16, 64);
        s += __shfl_xor(s, 32, 64);
        if (l < 16) out[((size_t)b << 11) + 1056 + l] = fmaxf(sqrtf(s), EPSN);
    }
}

// ============================ Kernel 2: sequential scan ============================
// One wave (block=64) per batch. Reads staging from out, overwrites with S_new.
__global__ __launch_bounds__(64, 3)
void scan_kernel(const float* __restrict__ Sg,      // [B,32,64]
                 const float* __restrict__ W_gw,    // [64,128]
                 const float* __restrict__ W_gb,    // [64]
                 float* __restrict__ out, int B)
{
    const int l = threadIdx.x;
    const int b = blockIdx.x;

    __shared__ float sS [32*68];
    __shared__ float snf[16*68];
    __shared__ float sm [96];    // alpha@0[32] fire@32 dconf@48 ncand@64

    // meta
    if (l < 48) sm[32 + l] = out[((size_t)b << 11) + 1024 + l];

    // load S (b128) -> LDS
    const float* Sb = Sg + ((size_t)b << 11);
    #pragma unroll
    for (int i = 0; i < 8; i++) {
        v4f v = *(const v4f*)&Sb[i*256 + l*4];
        *(v4f*)&sS[(i*4 + (l >> 4))*68 + (l & 15)*4] = v;
    }
    // load new_fact staging (b128) -> LDS
    const float* nfb = out + ((size_t)b << 11);
    #pragma unroll
    for (int i = 0; i < 4; i++) {
        v4f v = *(const v4f*)&nfb[i*256 + l*4];
        *(v4f*)&snf[(i*4 + (l >> 4))*68 + (l & 15)*4] = v;
    }

    // gamma weights to regs
    v2f wA[32], wB[32];
    {
        const v4f* w1 = (const v4f*)(W_gw + ((size_t)l << 7));
        const v4f* w2 = (const v4f*)(W_gw + ((size_t)l << 7) + 64);
        #pragma unroll
        for (int i = 0; i < 16; i++) {
            v4f a = w1[i]; wA[2*i] = a.xy; wA[2*i+1] = a.zw;
            v4f cc = w2[i]; wB[2*i] = cc.xy; wB[2*i+1] = cc.zw;
        }
    }
    const float gb = W_gb[l];

    const int m = l & 31, h = l >> 5;
    float nsd;
    {
        const v4f* sr = (const v4f*)&sS[m*68 + h*32];
        v2f s2 = {0.f, 0.f};
        #pragma unroll
        for (int i = 0; i < 8; i++) { v4f v = sr[i]; pk4(s2, v, v); }
        float s = hsum(s2);
        s += __shfl_xor(s, 32, 64);
        nsd = fmaxf(sqrtf(s), EPSN);
    }

    #pragma unroll 1
    for (int k = 0; k < 16; k++) {
        const float fire = sm[32 + k];        // wave-uniform
        if (fire <= 0.1f) continue;
        const float dck = sm[48 + k];
        const float ncn = sm[64 + k];         // ||cand||

        // dot[m] = cand . S[m]
        v2f d2 = {0.f, 0.f};
        {
            const v4f* sr = (const v4f*)&sS[m*68 + h*32];
            const v4f* cr = (const v4f*)&snf[k*68 + h*32];
            #pragma unroll
            for (int i = 0; i < 8; i++) pk4(d2, sr[i], cr[i]);
        }
        float dt = hsum(d2);
        dt += __shfl_xor(dt, 32, 64);
        const float sc = dt / (ncn * nsd);

        // softmax(4*sc) over 32 slots
        const float x = sc * 4.0f;
        float mx = x;
        mx = fmaxf(mx, __shfl_xor(mx, 1, 64));
        mx = fmaxf(mx, __shfl_xor(mx, 2, 64));
        mx = fmaxf(mx, __shfl_xor(mx, 4, 64));
        mx = fmaxf(mx, __shfl_xor(mx, 8, 64));
        mx = fmaxf(mx, __shfl_xor(mx, 16, 64));
        const float e = expf(x - mx);
        float se = e;
        se += __shfl_xor(se, 1, 64);
        se += __shfl_xor(se, 2, 64);
        se += __shfl_xor(se, 4, 64);
        se += __shfl_xor(se, 8, 64);
        se += __shfl_xor(se, 16, 64);
        const float alpha = e / se;

        // argmax(alpha), first index on ties
        float av = alpha; int ai = m;
        #pragma unroll
        for (int msk = 1; msk <= 16; msk <<= 1) {
            float ov = __shfl_xor(av, msk, 64);
            int   oi = __shfl_xor(ai, msk, 64);
            if (ov > av || (ov == av && oi < ai)) { av = ov; ai = oi; }
        }
        const int best = ai;                  // wave-uniform

        if (l < 32) sm[l] = alpha;

        // gamma = sigmoid([best_slot|cand] @ W_gw^T + b)
        v2f g2 = {0.f, 0.f};
        {
            const v4f* br = (const v4f*)&sS[best*68];
            const v4f* cr = (const v4f*)&snf[k*68];
            #pragma unroll
            for (int i = 0; i < 16; i++) {
                v4f bb = br[i]; g2 += bb.xy*wA[2*i]; g2 += bb.zw*wA[2*i+1];
                v4f cc = cr[i]; g2 += cc.xy*wB[2*i]; g2 += cc.zw*wB[2*i+1];
            }
        }
        const float g = gb + hsum(g2);
        const float gamma = 1.0f / (1.0f + expf(-g));
        const float cd  = snf[k*68 + l];
        const float bsd = sS[best*68 + l];
        const float ncd = gamma*cd + (1.0f - gamma)*bsd;
        const v2f ncd2 = {ncd, ncd};

        // S[m][d] += dconf * alpha[m] * (ncd[d] - S[m][d])   (packed, 2 rows/op)
        #pragma unroll
        for (int mg = 0; mg < 8; mg++) {
            v4f a4 = *(const v4f*)&sm[mg*4];
            v2f da0 = dck * a4.xy;
            v2f da1 = dck * a4.zw;
            const int base = (mg*4)*68 + l;
            float s0 = sS[base], s1v = sS[base+68], s2v = sS[base+136], s3v = sS[base+204];
            v2f s01 = {s0, s1v}, s23 = {s2v, s3v};
            s01 += da0 * (ncd2 - s01);
            s23 += da1 * (ncd2 - s23);
            sS[base] = s01.x; sS[base+68] = s01.y; sS[base+136] = s23.x; sS[base+204] = s23.y;
        }

        // refresh own-slot norm
        {
            const v4f* sr = (const v4f*)&sS[m*68 + h*32];
            v2f s2 = {0.f, 0.f};
            #pragma unroll
            for (int i = 0; i < 8; i++) { v4f v = sr[i]; pk4(s2, v, v); }
            float s = hsum(s2);
            s += __shfl_xor(s, 32, 64);
            nsd = fmaxf(sqrtf(s), EPSN);
        }
    }

    // store S_new (overwrites staging)
    #pragma unroll
    for (int i = 0; i < 8; i++) {
        v4f v = *(const v4f*)&sS[(i*4 + (l >> 4))*68 + (l & 15)*4];
        *(v4f*)&out[((size_t)b << 11) + i*256 + l*4] = v;
    }
}

extern "C" void kernel_launch(void* const* d_in, const int* in_sizes, int n_in,
                              void* d_out, int out_size, void* d_ws, size_t ws_size,
                              hipStream_t stream) {
    const float* content = (const float*)d_in[0];
    const float* types   = (const float*)d_in[1];
    const float* conf    = (const float*)d_in[2];
    const float* S       = (const float*)d_in[3];
    const float* W_ante  = (const float*)d_in[4];
    const float* W_cons  = (const float*)d_in[5];
    const float* W_gw    = (const float*)d_in[6];
    const float* W_gb    = (const float*)d_in[7];
    const float* lft     = (const float*)d_in[8];

    const int B = in_sizes[0] / 1024;

    hipLaunchKernelGGL(dense_kernel, dim3((B + 1) / 2), dim3(128), 0, stream,
                       content, types, conf, W_ante, W_cons, lft, (float*)d_out, B);
    hipLaunchKernelGGL(scan_kernel, dim3(B), dim3(64), 0, stream,
                       S, W_gw, W_gb, (float*)d_out, B);
}

// Round 3
// 368.539 us; speedup vs baseline: 1.3645x; 1.2538x over previous
//
#include <hip/hip_runtime.h>
#include <math.h>

typedef float v2f __attribute__((ext_vector_type(2)));
typedef float v4f __attribute__((ext_vector_type(4)));

#define EPSN 1e-8f

__device__ __forceinline__ float hsum(v2f a) { return a.x + a.y; }

__device__ __forceinline__ void pk4(v2f& acc, v4f a, v4f b) {
    acc += a.xy * b.xy;
    acc += a.zw * b.zw;
}

// ============================ Kernel 1: dense phase ============================
// One wave per batch. lane = output dim. No S / no scan -> small LDS, high occupancy.
// Stages new_fact + (fire, dconf, ||cand||) into d_out's per-batch S slot:
//   out[b*2048 + k*64 + d]   = new_fact[k][d]      (k = 0..15)
//   out[b*2048 + 1024 + l]   = fire[16] | dconf[16] | ncand[16]  (l = 0..47)
//   out[B*2048 + b]          = best_derived_conf (final output tail)
__global__ __launch_bounds__(128, 4)
void dense_kernel(const float* __restrict__ content,   // [B,16,64]
                  const float* __restrict__ types,     // [B,16,3]
                  const float* __restrict__ conf,      // [B,16]
                  const float* __restrict__ W_ante,    // [64,64]
                  const float* __restrict__ W_cons,    // [64,128]
                  const float* __restrict__ lft,       // [1]
                  float* __restrict__ out, int B)
{
    const int l = threadIdx.x & 63;
    const int w = threadIdx.x >> 6;
    const int b = blockIdx.x * 2 + w;
    if (b >= B) return;

    __shared__ float s_cont[2][16*68];   // content -> later new_fact
    __shared__ float s_scr [2][16*68];   // ante -> later matched
    __shared__ float s_ms  [2][16*20];   // match_scores
    __shared__ float s_sm  [2][96];      // conf@0 pf@16 pr@32 cn@48 an@64
    float* cont = s_cont[w];
    float* scr  = s_scr[w];
    float* ms   = s_ms[w];
    float* sm   = s_sm[w];

    const float thr = expf(lft[0]);

    // load content (regs + LDS), conf/types
    float c[16];
    const float* cb = content + ((size_t)b << 10);
    #pragma unroll
    for (int k = 0; k < 16; k++) {
        float v = cb[(k << 6) + l];
        c[k] = v;
        cont[k*68 + l] = v;
    }
    if (l < 16) {
        sm[0  + l] = conf[((size_t)b << 4) + l];
        sm[16 + l] = types[(((size_t)b << 4) + l)*3 + 0];   // p_fact
        sm[32 + l] = types[(((size_t)b << 4) + l)*3 + 1];   // p_rule
    }

    // content norms -> sm[48+k]
    {
        const int k = l & 15, q = l >> 4;
        const v4f* row = (const v4f*)&cont[k*68 + q*16];
        v2f s2 = {0.f, 0.f};
        #pragma unroll
        for (int i = 0; i < 4; i++) { v4f v = row[i]; pk4(s2, v, v); }
        float s = hsum(s2);
        s += __shfl_xor(s, 16, 64);
        s += __shfl_xor(s, 32, 64);
        if (l < 16) sm[48 + l] = fmaxf(sqrtf(s), EPSN);
    }

    // ante = content @ W_ante^T (W row resident in regs as v2f pairs)
    v2f wA[32];
    {
        const v4f* wr = (const v4f*)(W_ante + ((size_t)l << 6));
        #pragma unroll
        for (int i = 0; i < 16; i++) { v4f v = wr[i]; wA[2*i] = v.xy; wA[2*i+1] = v.zw; }
    }
    #pragma unroll
    for (int k = 0; k < 16; k++) {
        const v4f* cr = (const v4f*)&cont[k*68];
        v2f a = {0.f, 0.f};
        #pragma unroll
        for (int i = 0; i < 16; i++) { v4f v = cr[i]; a += v.xy*wA[2*i]; a += v.zw*wA[2*i+1]; }
        scr[k*68 + l] = hsum(a);
    }

    // ante norms -> sm[64+k]
    {
        const int k = l & 15, q = l >> 4;
        const v4f* row = (const v4f*)&scr[k*68 + q*16];
        v2f s2 = {0.f, 0.f};
        #pragma unroll
        for (int i = 0; i < 4; i++) { v4f v = row[i]; pk4(s2, v, v); }
        float s = hsum(s2);
        s += __shfl_xor(s, 16, 64);
        s += __shfl_xor(s, 32, 64);
        if (l < 16) sm[64 + l] = fmaxf(sqrtf(s), EPSN);
    }

    // dots + match_scores: lane -> (k = l&15, 4 j's)
    {
        const int k = l & 15, jg4 = (l >> 4) * 4;
        const v4f* ar = (const v4f*)&scr[k*68];
        const v4f* c0 = (const v4f*)&cont[(jg4+0)*68];
        const v4f* c1 = (const v4f*)&cont[(jg4+1)*68];
        const v4f* c2 = (const v4f*)&cont[(jg4+2)*68];
        const v4f* c3 = (const v4f*)&cont[(jg4+3)*68];
        v2f d0 = {0,0}, d1 = {0,0}, d2 = {0,0}, d3 = {0,0};
        #pragma unroll
        for (int i = 0; i < 16; i++) {
            v4f a = ar[i];
            v4f x0 = c0[i]; d0 += a.xy*x0.xy; d0 += a.zw*x0.zw;
            v4f x1 = c1[i]; d1 += a.xy*x1.xy; d1 += a.zw*x1.zw;
            v4f x2 = c2[i]; d2 += a.xy*x2.xy; d2 += a.zw*x2.zw;
            v4f x3 = c3[i]; d3 += a.xy*x3.xy; d3 += a.zw*x3.zw;
        }
        const float na = sm[64 + k];
        v4f res;
        res.x = (hsum(d0) / (na * sm[48 + jg4+0])) * sm[16 + jg4+0];
        res.y = (hsum(d1) / (na * sm[48 + jg4+1])) * sm[16 + jg4+1];
        res.z = (hsum(d2) / (na * sm[48 + jg4+2])) * sm[16 + jg4+2];
        res.w = (hsum(d3) / (na * sm[48 + jg4+3])) * sm[16 + jg4+3];
        *(v4f*)&ms[k*20 + jg4] = res;
    }

    // match_strength -> fire / dconf (lanes 0..15) -> staging + tail
    float dc_l = 0.f;
    if (l < 16) {
        const v4f* mr = (const v4f*)&ms[l*20];
        const v4f* cf = (const v4f*)&sm[0];
        v2f st = {0.f, 0.f};
        #pragma unroll
        for (int i = 0; i < 4; i++) { v4f m4 = mr[i]; v4f f4 = cf[i]; st += m4.xy*f4.xy; st += m4.zw*f4.zw; }
        float str = hsum(st);
        float fire = sm[32 + l] / (1.0f + expf(-(str - thr) * 2.0f));
        float dcf  = fire * sm[0 + l];
        out[((size_t)b << 11) + 1024 + l] = fire;
        out[((size_t)b << 11) + 1040 + l] = dcf;
        dc_l = dcf;
    }
    {
        float mv = dc_l;
        mv = fmaxf(mv, __shfl_xor(mv, 1, 64));
        mv = fmaxf(mv, __shfl_xor(mv, 2, 64));
        mv = fmaxf(mv, __shfl_xor(mv, 4, 64));
        mv = fmaxf(mv, __shfl_xor(mv, 8, 64));
        if (l == 0) out[((size_t)B << 11) + b] = mv;
    }

    // matched[k][d] = sum_j ms[k][j] * content[j][d]  (from regs c[])
    float mt[16];
    #pragma unroll
    for (int k = 0; k < 16; k++) {
        const v4f* mr = (const v4f*)&ms[k*20];
        v2f m2 = {0.f, 0.f};
        #pragma unroll
        for (int i = 0; i < 4; i++) {
            v4f m4 = mr[i];
            v2f clo = {c[4*i+0], c[4*i+1]};
            v2f chi = {c[4*i+2], c[4*i+3]};
            m2 += m4.xy*clo; m2 += m4.zw*chi;
        }
        mt[k] = hsum(m2);
    }
    #pragma unroll
    for (int k = 0; k < 16; k++) scr[k*68 + l] = mt[k];   // ante dead -> matched

    // new_fact = content @ W1^T + matched @ W2^T
    float nf[16];
    {
        const v4f* wr = (const v4f*)(W_cons + ((size_t)l << 7));
        #pragma unroll
        for (int i = 0; i < 16; i++) { v4f v = wr[i]; wA[2*i] = v.xy; wA[2*i+1] = v.zw; }
    }
    #pragma unroll
    for (int k = 0; k < 16; k++) {
        const v4f* cr = (const v4f*)&cont[k*68];
        v2f a = {0.f, 0.f};
        #pragma unroll
        for (int i = 0; i < 16; i++) { v4f v = cr[i]; a += v.xy*wA[2*i]; a += v.zw*wA[2*i+1]; }
        nf[k] = hsum(a);
    }
    {
        const v4f* wr = (const v4f*)(W_cons + ((size_t)l << 7) + 64);
        #pragma unroll
        for (int i = 0; i < 16; i++) { v4f v = wr[i]; wA[2*i] = v.xy; wA[2*i+1] = v.zw; }
    }
    #pragma unroll
    for (int k = 0; k < 16; k++) {
        const v4f* mr = (const v4f*)&scr[k*68];
        v2f a = {0.f, 0.f};
        #pragma unroll
        for (int i = 0; i < 16; i++) { v4f v = mr[i]; a += v.xy*wA[2*i]; a += v.zw*wA[2*i+1]; }
        nf[k] += hsum(a);
    }

    // nf -> LDS (for norms) + global staging
    #pragma unroll
    for (int k = 0; k < 16; k++) {
        cont[k*68 + l] = nf[k];
        out[((size_t)b << 11) + (k << 6) + l] = nf[k];
    }

    // ||cand|| -> staging
    {
        const int k = l & 15, q = l >> 4;
        const v4f* row = (const v4f*)&cont[k*68 + q*16];
        v2f s2 = {0.f, 0.f};
        #pragma unroll
        for (int i = 0; i < 4; i++) { v4f v = row[i]; pk4(s2, v, v); }
        float s = hsum(s2);
        s += __shfl_xor(s, 16, 64);
        s += __shfl_xor(s, 32, 64);
        if (l < 16) out[((size_t)b << 11) + 1056 + l] = fmaxf(sqrtf(s), EPSN);
    }
}

// ============================ Kernel 2: sequential scan ============================
// One wave (block=64) per batch.
// S register-resident (lane = d, 32 rows) with LDS write-through for m-layout reads.
// Gamma cand-half precomputed (wB streamed once); wA held resident in 64 VGPRs.
__global__ __launch_bounds__(64, 2)
void scan_kernel(const float* __restrict__ Sg,      // [B,32,64]
                 const float* __restrict__ W_gw,    // [64,128]
                 const float* __restrict__ W_gb,    // [64]
                 float* __restrict__ out, int B)
{
    const int l = threadIdx.x;
    const int b = blockIdx.x;

    __shared__ float sS   [32*68];   // S rows, pitch 68 (bank spread for per-lane row reads)
    __shared__ float snf  [16*64];   // new_fact rows, pitch 64 (broadcast reads only)
    __shared__ float smeta[48];      // fire[16] dconf[16] ncand[16]
    __shared__ float ebuf [32];      // un-normalized exp per slot

    // meta staging
    if (l < 48) smeta[l] = out[((size_t)b << 11) + 1024 + l];

    // new_fact staging -> LDS (flat b128 copy)
    const float* nfb = out + ((size_t)b << 11);
    #pragma unroll
    for (int i = 0; i < 4; i++) {
        *(v4f*)&snf[i*256 + l*4] = *(const v4f*)&nfb[i*256 + l*4];
    }

    // S -> regs (lane = d) + LDS write-through
    const float* Sb = Sg + ((size_t)b << 11);
    v2f Sreg[16];
    #pragma unroll
    for (int i = 0; i < 16; i++) {
        float a = Sb[(2*i)*64 + l];
        float c = Sb[(2*i+1)*64 + l];
        Sreg[i].x = a; Sreg[i].y = c;
        sS[(2*i)*68 + l] = a;
        sS[(2*i+1)*68 + l] = c;
    }

    const float gb = W_gb[l];

    // precompute gc[k] = cand_k . W_gw[l][64:128]  (wB streamed once, then dead)
    float gc[16];
    {
        v2f wB[32];
        const v4f* w2 = (const v4f*)(W_gw + ((size_t)l << 7) + 64);
        #pragma unroll
        for (int i = 0; i < 16; i++) { v4f v = w2[i]; wB[2*i] = v.xy; wB[2*i+1] = v.zw; }
        #pragma unroll
        for (int k = 0; k < 16; k++) {
            const v4f* cr = (const v4f*)&snf[k*64];
            v2f a = {0.f, 0.f};
            #pragma unroll
            for (int i = 0; i < 16; i++) { v4f v = cr[i]; a += v.xy*wB[2*i]; a += v.zw*wB[2*i+1]; }
            gc[k] = hsum(a);
        }
    }

    // wA (best-slot half of W_gw) resident for the loop
    v2f wA[32];
    {
        const v4f* w1 = (const v4f*)(W_gw + ((size_t)l << 7));
        #pragma unroll
        for (int i = 0; i < 16; i++) { v4f v = w1[i]; wA[2*i] = v.xy; wA[2*i+1] = v.zw; }
    }

    const int m = l & 31, h = l >> 5;

    #pragma unroll 1
    for (int k = 0; k < 16; k++) {
        const float fire = smeta[k];          // wave-uniform
        if (fire <= 0.1f) continue;
        const float dck = smeta[16 + k];
        const float ncn = smeta[32 + k];      // ||cand||

        // fused: dot[m] = cand.S[m] AND ||S[m]||^2 from the same row reads
        v2f d2 = {0.f, 0.f}, n2 = {0.f, 0.f};
        {
            const v4f* sr = (const v4f*)&sS[m*68 + h*32];
            const v4f* cr = (const v4f*)&snf[k*64 + h*32];
            #pragma unroll
            for (int i = 0; i < 8; i++) {
                v4f s = sr[i], c = cr[i];
                d2 += s.xy*c.xy; d2 += s.zw*c.zw;
                n2 += s.xy*s.xy; n2 += s.zw*s.zw;
            }
        }
        float dt = hsum(d2);
        float nn = hsum(n2);
        dt += __shfl_xor(dt, 32, 64);
        nn += __shfl_xor(nn, 32, 64);
        const float nsd = fmaxf(sqrtf(nn), EPSN);
        const float sc = dt / (ncn * nsd);

        // un-normalized softmax weight (|4*sc| <= ~4: no max-subtract needed)
        const float e = __expf(4.0f * sc);
        if (l < 32) ebuf[l] = e;

        // sum over 32 slots (both 32-halves hold duplicates -> consistent)
        float se = e;
        se += __shfl_xor(se, 1, 64);
        se += __shfl_xor(se, 2, 64);
        se += __shfl_xor(se, 4, 64);
        se += __shfl_xor(se, 8, 64);
        se += __shfl_xor(se, 16, 64);

        // argmax on sc (exp/div monotone -> same winner), first index on ties
        float av = sc; int ai = m;
        #pragma unroll
        for (int msk = 1; msk <= 16; msk <<= 1) {
            float ov = __shfl_xor(av, msk, 64);
            int   oi = __shfl_xor(ai, msk, 64);
            if (ov > av || (ov == av && oi < ai)) { av = ov; ai = oi; }
        }
        const int best = ai;                  // wave-uniform

        // gamma = sigmoid(best_slot.wA + cand.wB + b); cand-half precomputed
        v2f g2 = {0.f, 0.f};
        {
            const v4f* br = (const v4f*)&sS[best*68];   // broadcast reads
            #pragma unroll
            for (int i = 0; i < 16; i++) { v4f v = br[i]; g2 += v.xy*wA[2*i]; g2 += v.zw*wA[2*i+1]; }
        }
        const float g = gb + gc[k] + hsum(g2);
        const float gamma = 1.0f / (1.0f + __expf(-g));
        const float cd  = snf[k*64 + l];
        const float bsd = sS[best*68 + l];
        const float ncd = gamma*cd + (1.0f - gamma)*bsd;
        const v2f ncd2 = {ncd, ncd};
        const float dse = dck / se;

        // S[m][d] += (dck*e[m]/se) * (ncd[d] - S[m][d]); regs + write-through
        #pragma unroll
        for (int mg = 0; mg < 8; mg++) {
            v4f e4 = *(const v4f*)&ebuf[mg*4];
            v2f w01 = dse * e4.xy;
            v2f w23 = dse * e4.zw;
            Sreg[2*mg]   += w01 * (ncd2 - Sreg[2*mg]);
            Sreg[2*mg+1] += w23 * (ncd2 - Sreg[2*mg+1]);
            const int base = (mg*4)*68 + l;
            sS[base      ] = Sreg[2*mg].x;
            sS[base +  68] = Sreg[2*mg].y;
            sS[base + 136] = Sreg[2*mg+1].x;
            sS[base + 204] = Sreg[2*mg+1].y;
        }
    }

    // store S_new from regs (overwrites staging region)
    float* ob = out + ((size_t)b << 11);
    #pragma unroll
    for (int i = 0; i < 16; i++) {
        ob[(2*i)*64 + l]   = Sreg[i].x;
        ob[(2*i+1)*64 + l] = Sreg[i].y;
    }
}

extern "C" void kernel_launch(void* const* d_in, const int* in_sizes, int n_in,
                              void* d_out, int out_size, void* d_ws, size_t ws_size,
                              hipStream_t stream) {
    const float* content = (const float*)d_in[0];
    const float* types   = (const float*)d_in[1];
    const float* conf    = (const float*)d_in[2];
    const float* S       = (const float*)d_in[3];
    const float* W_ante  = (const float*)d_in[4];
    const float* W_cons  = (const float*)d_in[5];
    const float* W_gw    = (const float*)d_in[6];
    const float* W_gb    = (const float*)d_in[7];
    const float* lft     = (const float*)d_in[8];

    const int B = in_sizes[0] / 1024;

    hipLaunchKernelGGL(dense_kernel, dim3((B + 1) / 2), dim3(128), 0, stream,
                       content, types, conf, W_ante, W_cons, lft, (float*)d_out, B);
    hipLaunchKernelGGL(scan_kernel, dim3(B), dim3(64), 0, stream,
                       S, W_gw, W_gb, (float*)d_out, B);
}

// Round 4
// 335.829 us; speedup vs baseline: 1.4974x; 1.0974x over previous
//
#include <hip/hip_runtime.h>
#include <math.h>

typedef float v2f __attribute__((ext_vector_type(2)));
typedef float v4f __attribute__((ext_vector_type(4)));

__device__ __forceinline__ float hsum(v2f a) { return a.x + a.y; }
__device__ __forceinline__ float rsq_(float x) { return __builtin_amdgcn_rsqf(fmaxf(x, 1e-16f)); }
__device__ __forceinline__ float rcp_(float x) { return __builtin_amdgcn_rcpf(x); }

__device__ __forceinline__ void pk4(v2f& acc, v4f a, v4f b) {
    acc += a.xy * b.xy;
    acc += a.zw * b.zw;
}

// ============================ Kernel 1: dense phase ============================
// One wave per batch. lane = output dim. Stages into d_out's per-batch S slot:
//   out[b*2048 + k*64 + d]   = new_fact[k][d]
//   out[b*2048 + 1024 + l]   = fire[16] | dconf[16] | 1/||cand||[16]
//   out[B*2048 + b]          = best_derived_conf
__global__ __launch_bounds__(128, 4)
void dense_kernel(const float* __restrict__ content,   // [B,16,64]
                  const float* __restrict__ types,     // [B,16,3]
                  const float* __restrict__ conf,      // [B,16]
                  const float* __restrict__ W_ante,    // [64,64]
                  const float* __restrict__ W_cons,    // [64,128]
                  const float* __restrict__ lft,       // [1]
                  float* __restrict__ out, int B)
{
    const int l = threadIdx.x & 63;
    const int w = threadIdx.x >> 6;
    const int b = blockIdx.x * 2 + w;
    if (b >= B) return;

    __shared__ float s_cont[2][16*68];   // content -> later new_fact
    __shared__ float s_scr [2][16*68];   // ante -> later matched
    __shared__ float s_ms  [2][16*20];   // match_scores
    __shared__ float s_sm  [2][96];      // conf@0 pf@16 pr@32 rcn@48 ran@64
    float* cont = s_cont[w];
    float* scr  = s_scr[w];
    float* ms   = s_ms[w];
    float* sm   = s_sm[w];

    const float thr = expf(lft[0]);

    // load content (regs + LDS), conf/types
    float c[16];
    const float* cb = content + ((size_t)b << 10);
    #pragma unroll
    for (int k = 0; k < 16; k++) {
        float v = cb[(k << 6) + l];
        c[k] = v;
        cont[k*68 + l] = v;
    }
    if (l < 16) {
        sm[0  + l] = conf[((size_t)b << 4) + l];
        sm[16 + l] = types[(((size_t)b << 4) + l)*3 + 0];   // p_fact
        sm[32 + l] = types[(((size_t)b << 4) + l)*3 + 1];   // p_rule
    }

    // content inverse norms -> sm[48+k]
    {
        const int k = l & 15, q = l >> 4;
        const v4f* row = (const v4f*)&cont[k*68 + q*16];
        v2f s2 = {0.f, 0.f};
        #pragma unroll
        for (int i = 0; i < 4; i++) { v4f v = row[i]; pk4(s2, v, v); }
        float s = hsum(s2);
        s += __shfl_xor(s, 16, 64);
        s += __shfl_xor(s, 32, 64);
        if (l < 16) sm[48 + l] = rsq_(s);
    }

    // ante = content @ W_ante^T (W row resident in regs as v2f pairs)
    v2f wA[32];
    {
        const v4f* wr = (const v4f*)(W_ante + ((size_t)l << 6));
        #pragma unroll
        for (int i = 0; i < 16; i++) { v4f v = wr[i]; wA[2*i] = v.xy; wA[2*i+1] = v.zw; }
    }
    #pragma unroll
    for (int k = 0; k < 16; k++) {
        const v4f* cr = (const v4f*)&cont[k*68];
        v2f a = {0.f, 0.f};
        #pragma unroll
        for (int i = 0; i < 16; i++) { v4f v = cr[i]; a += v.xy*wA[2*i]; a += v.zw*wA[2*i+1]; }
        scr[k*68 + l] = hsum(a);
    }

    // ante inverse norms -> sm[64+k]
    {
        const int k = l & 15, q = l >> 4;
        const v4f* row = (const v4f*)&scr[k*68 + q*16];
        v2f s2 = {0.f, 0.f};
        #pragma unroll
        for (int i = 0; i < 4; i++) { v4f v = row[i]; pk4(s2, v, v); }
        float s = hsum(s2);
        s += __shfl_xor(s, 16, 64);
        s += __shfl_xor(s, 32, 64);
        if (l < 16) sm[64 + l] = rsq_(s);
    }

    // dots + match_scores: lane -> (k = l&15, 4 j's); sim = dot * ran * rcn * pf
    {
        const int k = l & 15, jg4 = (l >> 4) * 4;
        const v4f* ar = (const v4f*)&scr[k*68];
        const v4f* c0 = (const v4f*)&cont[(jg4+0)*68];
        const v4f* c1 = (const v4f*)&cont[(jg4+1)*68];
        const v4f* c2 = (const v4f*)&cont[(jg4+2)*68];
        const v4f* c3 = (const v4f*)&cont[(jg4+3)*68];
        v2f d0 = {0,0}, d1 = {0,0}, d2 = {0,0}, d3 = {0,0};
        #pragma unroll
        for (int i = 0; i < 16; i++) {
            v4f a = ar[i];
            v4f x0 = c0[i]; d0 += a.xy*x0.xy; d0 += a.zw*x0.zw;
            v4f x1 = c1[i]; d1 += a.xy*x1.xy; d1 += a.zw*x1.zw;
            v4f x2 = c2[i]; d2 += a.xy*x2.xy; d2 += a.zw*x2.zw;
            v4f x3 = c3[i]; d3 += a.xy*x3.xy; d3 += a.zw*x3.zw;
        }
        const float ra = sm[64 + k];
        v4f res;
        res.x = hsum(d0) * ra * sm[48 + jg4+0] * sm[16 + jg4+0];
        res.y = hsum(d1) * ra * sm[48 + jg4+1] * sm[16 + jg4+1];
        res.z = hsum(d2) * ra * sm[48 + jg4+2] * sm[16 + jg4+2];
        res.w = hsum(d3) * ra * sm[48 + jg4+3] * sm[16 + jg4+3];
        *(v4f*)&ms[k*20 + jg4] = res;
    }

    // match_strength -> fire / dconf (lanes 0..15) -> staging + tail
    float dc_l = 0.f;
    if (l < 16) {
        const v4f* mr = (const v4f*)&ms[l*20];
        const v4f* cf = (const v4f*)&sm[0];
        v2f st = {0.f, 0.f};
        #pragma unroll
        for (int i = 0; i < 4; i++) { v4f m4 = mr[i]; v4f f4 = cf[i]; st += m4.xy*f4.xy; st += m4.zw*f4.zw; }
        float str = hsum(st);
        float fire = sm[32 + l] * rcp_(1.0f + __expf(-(str - thr) * 2.0f));
        float dcf  = fire * sm[0 + l];
        out[((size_t)b << 11) + 1024 + l] = fire;
        out[((size_t)b << 11) + 1040 + l] = dcf;
        dc_l = dcf;
    }
    {
        float mv = dc_l;
        mv = fmaxf(mv, __shfl_xor(mv, 1, 64));
        mv = fmaxf(mv, __shfl_xor(mv, 2, 64));
        mv = fmaxf(mv, __shfl_xor(mv, 4, 64));
        mv = fmaxf(mv, __shfl_xor(mv, 8, 64));
        if (l == 0) out[((size_t)B << 11) + b] = mv;
    }

    // matched[k][d] = sum_j ms[k][j] * content[j][d]  (from regs c[])
    float mt[16];
    #pragma unroll
    for (int k = 0; k < 16; k++) {
        const v4f* mr = (const v4f*)&ms[k*20];
        v2f m2 = {0.f, 0.f};
        #pragma unroll
        for (int i = 0; i < 4; i++) {
            v4f m4 = mr[i];
            v2f clo = {c[4*i+0], c[4*i+1]};
            v2f chi = {c[4*i+2], c[4*i+3]};
            m2 += m4.xy*clo; m2 += m4.zw*chi;
        }
        mt[k] = hsum(m2);
    }
    #pragma unroll
    for (int k = 0; k < 16; k++) scr[k*68 + l] = mt[k];   // ante dead -> matched

    // new_fact = content @ W1^T + matched @ W2^T
    float nf[16];
    {
        const v4f* wr = (const v4f*)(W_cons + ((size_t)l << 7));
        #pragma unroll
        for (int i = 0; i < 16; i++) { v4f v = wr[i]; wA[2*i] = v.xy; wA[2*i+1] = v.zw; }
    }
    #pragma unroll
    for (int k = 0; k < 16; k++) {
        const v4f* cr = (const v4f*)&cont[k*68];
        v2f a = {0.f, 0.f};
        #pragma unroll
        for (int i = 0; i < 16; i++) { v4f v = cr[i]; a += v.xy*wA[2*i]; a += v.zw*wA[2*i+1]; }
        nf[k] = hsum(a);
    }
    {
        const v4f* wr = (const v4f*)(W_cons + ((size_t)l << 7) + 64);
        #pragma unroll
        for (int i = 0; i < 16; i++) { v4f v = wr[i]; wA[2*i] = v.xy; wA[2*i+1] = v.zw; }
    }
    #pragma unroll
    for (int k = 0; k < 16; k++) {
        const v4f* mr = (const v4f*)&scr[k*68];
        v2f a = {0.f, 0.f};
        #pragma unroll
        for (int i = 0; i < 16; i++) { v4f v = mr[i]; a += v.xy*wA[2*i]; a += v.zw*wA[2*i+1]; }
        nf[k] += hsum(a);
    }

    // nf -> LDS (for norms) + global staging
    #pragma unroll
    for (int k = 0; k < 16; k++) {
        cont[k*68 + l] = nf[k];
        out[((size_t)b << 11) + (k << 6) + l] = nf[k];
    }

    // 1/||cand|| -> staging
    {
        const int k = l & 15, q = l >> 4;
        const v4f* row = (const v4f*)&cont[k*68 + q*16];
        v2f s2 = {0.f, 0.f};
        #pragma unroll
        for (int i = 0; i < 4; i++) { v4f v = row[i]; pk4(s2, v, v); }
        float s = hsum(s2);
        s += __shfl_xor(s, 16, 64);
        s += __shfl_xor(s, 32, 64);
        if (l < 16) out[((size_t)b << 11) + 1056 + l] = rsq_(s);
    }
}

// ============================ Kernel 2: sequential scan ============================
// 4 batches per block (4 independent waves, no barriers). S register-resident
// (lane = d) with LDS write-through for m-layout reads. wA/gc register-resident.
__global__ __launch_bounds__(256, 3)
void scan_kernel(const float* __restrict__ Sg,      // [B,32,64]
                 const float* __restrict__ W_gw,    // [64,128]
                 const float* __restrict__ W_gb,    // [64]
                 float* __restrict__ out, int B)
{
    const int l = threadIdx.x & 63;
    const int w = threadIdx.x >> 6;
    const int b = (blockIdx.x << 2) + w;
    if (b >= B) return;

    __shared__ float sS_   [4][32*68];   // S rows, pitch 68
    __shared__ float snf_  [4][16*64];   // new_fact rows, pitch 64 (broadcast reads)
    __shared__ float smeta_[4][48];      // fire[16] dconf[16] 1/||cand||[16]
    __shared__ float ebuf_ [4][32];      // pre-scaled update weight per slot
    float* sS    = sS_[w];
    float* snf   = snf_[w];
    float* smeta = smeta_[w];
    float* ebuf  = ebuf_[w];

    // meta staging
    if (l < 48) smeta[l] = out[((size_t)b << 11) + 1024 + l];

    // new_fact staging -> LDS (flat b128 copy)
    const float* nfb = out + ((size_t)b << 11);
    #pragma unroll
    for (int i = 0; i < 4; i++) {
        *(v4f*)&snf[i*256 + l*4] = *(const v4f*)&nfb[i*256 + l*4];
    }

    // S -> LDS pitch-68 via b128 (8 loads + 8 writes)
    const float* Sb = Sg + ((size_t)b << 11);
    #pragma unroll
    for (int i = 0; i < 8; i++) {
        const int r = i*4 + (l >> 4), q = (l & 15) * 4;
        *(v4f*)&sS[r*68 + q] = *(const v4f*)&Sb[r*64 + q];
    }
    // S -> regs (lane = d)
    v2f Sreg[16];
    #pragma unroll
    for (int i = 0; i < 16; i++) {
        Sreg[i].x = Sb[(2*i)*64 + l];
        Sreg[i].y = Sb[(2*i+1)*64 + l];
    }

    const float gb = W_gb[l];

    // precompute gc[k] = cand_k . W_gw[l][64:128]  (wB streamed once, then dead)
    float gc[16];
    {
        v2f wB[32];
        const v4f* w2 = (const v4f*)(W_gw + ((size_t)l << 7) + 64);
        #pragma unroll
        for (int i = 0; i < 16; i++) { v4f v = w2[i]; wB[2*i] = v.xy; wB[2*i+1] = v.zw; }
        #pragma unroll
        for (int k = 0; k < 16; k++) {
            const v4f* cr = (const v4f*)&snf[k << 6];
            v2f a = {0.f, 0.f};
            #pragma unroll
            for (int i = 0; i < 16; i++) { v4f v = cr[i]; a += v.xy*wB[2*i]; a += v.zw*wB[2*i+1]; }
            gc[k] = hsum(a);
        }
    }

    // wA (best-slot half of W_gw) resident for the loop
    v2f wA[32];
    {
        const v4f* w1 = (const v4f*)(W_gw + ((size_t)l << 7));
        #pragma unroll
        for (int i = 0; i < 16; i++) { v4f v = w1[i]; wA[2*i] = v.xy; wA[2*i+1] = v.zw; }
    }

    const int m = l & 31, h = l >> 5;

    #pragma unroll 1
    for (int k = 0; k < 16; k++) {
        const float fire = smeta[k];          // wave-uniform
        if (fire <= 0.1f) continue;
        const float dck  = smeta[16 + k];
        const float rncn = smeta[32 + k];     // 1/||cand||

        // fused: dot[m] = cand.S[m] AND ||S[m]||^2 from the same row reads
        v2f d2 = {0.f, 0.f}, n2 = {0.f, 0.f};
        {
            const v4f* sr = (const v4f*)&sS[m*68 + h*32];
            const v4f* cr = (const v4f*)&snf[(k << 6) + h*32];
            #pragma unroll
            for (int i = 0; i < 8; i++) {
                v4f s = sr[i], c = cr[i];
                d2 += s.xy*c.xy; d2 += s.zw*c.zw;
                n2 += s.xy*s.xy; n2 += s.zw*s.zw;
            }
        }
        float dt = hsum(d2);
        float nn = hsum(n2);
        dt += __shfl_xor(dt, 32, 64);
        nn += __shfl_xor(nn, 32, 64);
        const float sc = dt * rsq_(nn) * rncn;

        // un-normalized softmax weight (|4*sc| <= ~4: no max-subtract needed)
        const float e = __expf(4.0f * sc);
        float se = e;
        se += __shfl_xor(se, 1, 64);
        se += __shfl_xor(se, 2, 64);
        se += __shfl_xor(se, 4, 64);
        se += __shfl_xor(se, 8, 64);
        se += __shfl_xor(se, 16, 64);

        // argmax via max-reduce + ballot (first index on ties, halves duplicate)
        float mxv = sc;
        mxv = fmaxf(mxv, __shfl_xor(mxv, 1, 64));
        mxv = fmaxf(mxv, __shfl_xor(mxv, 2, 64));
        mxv = fmaxf(mxv, __shfl_xor(mxv, 4, 64));
        mxv = fmaxf(mxv, __shfl_xor(mxv, 8, 64));
        mxv = fmaxf(mxv, __shfl_xor(mxv, 16, 64));
        const unsigned long long bal = __ballot(sc == mxv);
        const int best = __ffsll(bal & 0xffffffffULL) - 1;   // wave-uniform

        // pre-scaled per-slot update weight: dck * e[m] / se
        const float wse = dck * rcp_(se);
        if (l < 32) ebuf[l] = e * wse;

        // gamma = sigmoid(best_slot.wA + cand.wB + b); cand-half precomputed
        v2f g2 = {0.f, 0.f};
        {
            const v4f* br = (const v4f*)&sS[best*68];   // broadcast reads
            #pragma unroll
            for (int i = 0; i < 16; i++) { v4f v = br[i]; g2 += v.xy*wA[2*i]; g2 += v.zw*wA[2*i+1]; }
        }
        const float g = gb + gc[k] + hsum(g2);
        const float gamma = rcp_(1.0f + __expf(-g));
        const float cd  = snf[(k << 6) + l];
        const float bsd = sS[best*68 + l];
        const float ncd = gamma*cd + (1.0f - gamma)*bsd;
        const v2f ncd2 = {ncd, ncd};

        // S[m][d] += w[m] * (ncd[d] - S[m][d]); regs + write-through
        #pragma unroll
        for (int mg = 0; mg < 8; mg++) {
            v4f e4 = *(const v4f*)&ebuf[mg*4];
            Sreg[2*mg]   += e4.xy * (ncd2 - Sreg[2*mg]);
            Sreg[2*mg+1] += e4.zw * (ncd2 - Sreg[2*mg+1]);
            const int base = (mg*4)*68 + l;
            sS[base      ] = Sreg[2*mg].x;
            sS[base +  68] = Sreg[2*mg].y;
            sS[base + 136] = Sreg[2*mg+1].x;
            sS[base + 204] = Sreg[2*mg+1].y;
        }
    }

    // store S_new from regs (overwrites staging region)
    float* ob = out + ((size_t)b << 11);
    #pragma unroll
    for (int i = 0; i < 16; i++) {
        ob[(2*i)*64 + l]   = Sreg[i].x;
        ob[(2*i+1)*64 + l] = Sreg[i].y;
    }
}

extern "C" void kernel_launch(void* const* d_in, const int* in_sizes, int n_in,
                              void* d_out, int out_size, void* d_ws, size_t ws_size,
                              hipStream_t stream) {
    const float* content = (const float*)d_in[0];
    const float* types   = (const float*)d_in[1];
    const float* conf    = (const float*)d_in[2];
    const float* S       = (const float*)d_in[3];
    const float* W_ante  = (const float*)d_in[4];
    const float* W_cons  = (const float*)d_in[5];
    const float* W_gw    = (const float*)d_in[6];
    const float* W_gb    = (const float*)d_in[7];
    const float* lft     = (const float*)d_in[8];

    const int B = in_sizes[0] / 1024;

    hipLaunchKernelGGL(dense_kernel, dim3((B + 1) / 2), dim3(128), 0, stream,
                       content, types, conf, W_ante, W_cons, lft, (float*)d_out, B);
    hipLaunchKernelGGL(scan_kernel, dim3((B + 3) / 4), dim3(256), 0, stream,
                       S, W_gw, W_gb, (float*)d_out, B);
}